// Round 3
// baseline (180.124 us; speedup 1.0000x reference)
//
#include <hip/hip_runtime.h>
#include <hip/hip_bf16.h>

typedef unsigned short ushort_t;
typedef __attribute__((ext_vector_type(8))) short short8;   // 8 bf16 (4 VGPRs)
typedef __attribute__((ext_vector_type(4))) short short4v;  // 4 bf16 (2 VGPRs)
typedef __attribute__((ext_vector_type(4))) float f32x4;    // 4 fp32 acc

__device__ __forceinline__ float bf2f(ushort_t u) {
    unsigned int x = ((unsigned int)u) << 16;
    float f; __builtin_memcpy(&f, &x, 4); return f;
}
__device__ __forceinline__ ushort_t f2bf(float f) {
    __hip_bfloat16 h = __float2bfloat16(f);
    ushort_t u; __builtin_memcpy(&u, &h, 2); return u;
}
__device__ __forceinline__ unsigned packbf2(float a, float b) {
    return (unsigned)f2bf(a) | ((unsigned)f2bf(b) << 16);
}

constexpr int E  = 1024;
constexpr int Hd = 64;
constexpr int S  = 2048;
constexpr int ROWS = 8 * 2048;   // 16384
constexpr int NTOT = 192;
constexpr int LST  = 88;         // proj LDS row stride

// ---------------------------------------------------------------------------
// prep: WT[192][1024] bf16, rows 0-63 = Wq^T, 64-127 = Wk^T, 128-191 = Wv^T
__global__ __launch_bounds__(256)
void prep_wt(const float* __restrict__ Wk, const float* __restrict__ Wq,
             const float* __restrict__ Wv, ushort_t* __restrict__ WT)
{
    int idx = blockIdx.x * 256 + threadIdx.x;
    int n = idx >> 10;
    int kk = idx & 1023;
    const float* W = (n < 64) ? Wq : ((n < 128) ? Wk : Wv);
    int h = n & 63;
    WT[idx] = f2bf(W[kk * Hd + h]);
}

// ---------------------------------------------------------------------------
// Projection v9 (unchanged from R2): 2-deep x prefetch + single-barrier
// double-buffered XS.
__global__ __launch_bounds__(256)
void proj_v7(const float* __restrict__ x, const ushort_t* __restrict__ WT,
             ushort_t* __restrict__ qo, ushort_t* __restrict__ ko,
             ushort_t* __restrict__ vTo)
{
    __shared__ alignas(16) ushort_t XS0[32][LST];
    __shared__ alignas(16) ushort_t XS1[32][LST];

    const int t    = threadIdx.x;
    const int w    = t >> 6;
    const int lane = t & 63;
    const int m    = lane & 15;
    const int g    = lane >> 4;
    const int rb   = blockIdx.x * 32;

    f32x4 accq[2], acck[2], accv[2];
    #pragma unroll
    for (int j = 0; j < 2; ++j) {
        accq[j] = (f32x4){0.f, 0.f, 0.f, 0.f};
        acck[j] = (f32x4){0.f, 0.f, 0.f, 0.f};
        accv[j] = (f32x4){0.f, 0.f, 0.f, 0.f};
    }

    const float* xptr = x + (size_t)(rb + (t >> 3)) * E + (t & 7) * 8;
    const ushort_t* wqp = WT + (size_t)(w * 16 + m) * E + g * 8;
    const ushort_t* wkp = wqp + (size_t)64 * E;
    const ushort_t* wvp = wqp + (size_t)128 * E;

    const int sr = t >> 3, sc = (t & 7) * 8;

    float4 xA0 = *(const float4*)xptr;
    float4 xA1 = *(const float4*)(xptr + 4);
    float4 xB0 = *(const float4*)(xptr + 64);
    float4 xB1 = *(const float4*)(xptr + 64 + 4);

    short8 wAq[2], wAk[2], wAv[2], wBq[2], wBk[2], wBv[2];
    #pragma unroll
    for (int kt = 0; kt < 2; ++kt) {
        wAq[kt] = *(const short8*)(wqp + kt * 32);
        wAk[kt] = *(const short8*)(wkp + kt * 32);
        wAv[kt] = *(const short8*)(wvp + kt * 32);
    }

    #pragma unroll 1
    for (int cc = 0; cc < 16; cc += 2) {
        // ---------------- even body: c = cc, buffer XS0, weights wA
        {
            uint4 sv;
            sv.x = packbf2(xA0.x, xA0.y);
            sv.y = packbf2(xA0.z, xA0.w);
            sv.z = packbf2(xA1.x, xA1.y);
            sv.w = packbf2(xA1.z, xA1.w);
            *(uint4*)&XS0[sr][sc] = sv;
        }
        __syncthreads();
        if (cc + 2 < 16) {
            const int k0 = (cc + 2) * 64;
            xA0 = *(const float4*)(xptr + k0);
            xA1 = *(const float4*)(xptr + k0 + 4);
        }
        {
            const int k0 = (cc + 1) * 64;
            #pragma unroll
            for (int kt = 0; kt < 2; ++kt) {
                wBq[kt] = *(const short8*)(wqp + k0 + kt * 32);
                wBk[kt] = *(const short8*)(wkp + k0 + kt * 32);
                wBv[kt] = *(const short8*)(wvp + k0 + kt * 32);
            }
        }
        #pragma unroll
        for (int kt = 0; kt < 2; ++kt) {
            short8 a0 = *(const short8*)&XS0[m][kt * 32 + g * 8];
            short8 a1 = *(const short8*)&XS0[16 + m][kt * 32 + g * 8];
            accq[0] = __builtin_amdgcn_mfma_f32_16x16x32_bf16(a0, wAq[kt], accq[0], 0, 0, 0);
            accq[1] = __builtin_amdgcn_mfma_f32_16x16x32_bf16(a1, wAq[kt], accq[1], 0, 0, 0);
            acck[0] = __builtin_amdgcn_mfma_f32_16x16x32_bf16(a0, wAk[kt], acck[0], 0, 0, 0);
            acck[1] = __builtin_amdgcn_mfma_f32_16x16x32_bf16(a1, wAk[kt], acck[1], 0, 0, 0);
            accv[0] = __builtin_amdgcn_mfma_f32_16x16x32_bf16(wAv[kt], a0, accv[0], 0, 0, 0);
            accv[1] = __builtin_amdgcn_mfma_f32_16x16x32_bf16(wAv[kt], a1, accv[1], 0, 0, 0);
        }

        // ---------------- odd body: c = cc+1, buffer XS1, weights wB
        {
            uint4 sv;
            sv.x = packbf2(xB0.x, xB0.y);
            sv.y = packbf2(xB0.z, xB0.w);
            sv.z = packbf2(xB1.x, xB1.y);
            sv.w = packbf2(xB1.z, xB1.w);
            *(uint4*)&XS1[sr][sc] = sv;
        }
        __syncthreads();
        if (cc + 3 < 16) {
            const int k0 = (cc + 3) * 64;
            xB0 = *(const float4*)(xptr + k0);
            xB1 = *(const float4*)(xptr + k0 + 4);
        }
        if (cc + 2 < 16) {
            const int k0 = (cc + 2) * 64;
            #pragma unroll
            for (int kt = 0; kt < 2; ++kt) {
                wAq[kt] = *(const short8*)(wqp + k0 + kt * 32);
                wAk[kt] = *(const short8*)(wkp + k0 + kt * 32);
                wAv[kt] = *(const short8*)(wvp + k0 + kt * 32);
            }
        }
        #pragma unroll
        for (int kt = 0; kt < 2; ++kt) {
            short8 a0 = *(const short8*)&XS1[m][kt * 32 + g * 8];
            short8 a1 = *(const short8*)&XS1[16 + m][kt * 32 + g * 8];
            accq[0] = __builtin_amdgcn_mfma_f32_16x16x32_bf16(a0, wBq[kt], accq[0], 0, 0, 0);
            accq[1] = __builtin_amdgcn_mfma_f32_16x16x32_bf16(a1, wBq[kt], accq[1], 0, 0, 0);
            acck[0] = __builtin_amdgcn_mfma_f32_16x16x32_bf16(a0, wBk[kt], acck[0], 0, 0, 0);
            acck[1] = __builtin_amdgcn_mfma_f32_16x16x32_bf16(a1, wBk[kt], acck[1], 0, 0, 0);
            accv[0] = __builtin_amdgcn_mfma_f32_16x16x32_bf16(wBv[kt], a0, accv[0], 0, 0, 0);
            accv[1] = __builtin_amdgcn_mfma_f32_16x16x32_bf16(wBv[kt], a1, accv[1], 0, 0, 0);
        }
    }

    const int col   = w * 16 + m;
    const int batch = rb >> 11;
    const int seq0  = rb & (S - 1);
    #pragma unroll
    for (int mt = 0; mt < 2; ++mt) {
        const int orow = rb + mt * 16 + g * 4;
        #pragma unroll
        for (int r = 0; r < 4; ++r) {
            qo[(size_t)(orow + r) * Hd + col] = f2bf(accq[mt][r] * 0.125f);
            ko[(size_t)(orow + r) * Hd + col] = f2bf(acck[mt][r]);
        }
    }
    #pragma unroll
    for (int ns = 0; ns < 2; ++ns)
        #pragma unroll
        for (int r = 0; r < 4; ++r) {
            const int h = w * 16 + g * 4 + r;
            vTo[(size_t)batch * Hd * S + (size_t)h * S + seq0 + ns * 16 + m]
                = f2bf(accv[ns][r]);
        }
}

// ---------------------------------------------------------------------------
// Attention v12 — LDS-FREE, BARRIER-FREE. Both MFMA fragment layouts are
// directly loadable from global (K/V per batch = 512 KB, L2-resident; the 4
// waves of a block re-touch the same 16 KB tile -> L1 hits). Each wave
// free-runs its key-tile loop: no __syncthreads, no ds traffic, no staging
// serialization. batch = blockIdx.x & 7 pins each batch's K/V working set to
// one XCD's L2 (8 batches <-> 8 XCDs).
__global__ __launch_bounds__(256)
void attn_part(const ushort_t* __restrict__ q, const ushort_t* __restrict__ k,
               const ushort_t* __restrict__ vT,
               float* __restrict__ lp, ushort_t* __restrict__ op)
{
    const int bi     = blockIdx.x;
    const int batch  = bi & 7;          // batch == XCD slot (L2 affinity)
    const int u      = bi >> 3;
    const int parity = u & 3;
    const int tile   = 31 - (u >> 2);   // longest-first
    const int qs0    = tile * 64;
    const int sidx   = (batch * 32 + tile) * 4 + parity;

    const ushort_t* kb  = k  + (size_t)batch * S * Hd;
    const ushort_t* vTb = vT + (size_t)batch * Hd * S;

    const int t    = threadIdx.x;
    const int w    = t >> 6;
    const int lane = t & 63;
    const int m    = lane & 15;
    const int g    = lane >> 4;

    const ushort_t* qrow = q + (size_t)(batch * S + qs0 + w * 16 + m) * Hd;
    short8 qf0 = *(const short8*)(qrow + g * 8);
    short8 qf1 = *(const short8*)(qrow + 32 + g * 8);

    f32x4 o[4];
    #pragma unroll
    for (int j = 0; j < 4; ++j) o[j] = (f32x4){0.f, 0.f, 0.f, 0.f};
    float lrun = 0.f;
    const int qr = w * 16 + m;   // this lane's q row (mask + l)

    // Per-lane fragment base addresses (lane-invariant parts folded in).
    const ushort_t* kAddr = kb  + (size_t)m * Hd + g * 8;   // + (key0+nt*16)*Hd (+32)
    const ushort_t* vAddr = vTb + (size_t)m * S  + g * 4;   // + nt*16*S + key0 + s*16

    #pragma unroll 1
    for (int c = parity; c <= tile; c += 4) {
        const int key0 = c * 64;

        // ---- K fragments straight from global (same semantics as old KS read)
        short8 kf[4][2];
        #pragma unroll
        for (int nt = 0; nt < 4; ++nt) {
            const ushort_t* p = kAddr + (size_t)(key0 + nt * 16) * Hd;
            kf[nt][0] = *(const short8*)p;
            kf[nt][1] = *(const short8*)(p + 32);
        }
        // ---- V fragments straight from global (same semantics as old VTS read)
        short4v vf[4][4];
        #pragma unroll
        for (int nt = 0; nt < 4; ++nt) {
            const ushort_t* p = vAddr + (size_t)(nt * 16) * S + key0;
            #pragma unroll
            for (int s = 0; s < 4; ++s)
                vf[nt][s] = *(const short4v*)(p + s * 16);
        }

        // ---- S^T = K Q^T: sacc[nt][r] = S[q = w*16+m][key = nt*16+g*4+r]
        f32x4 sacc[4];
        #pragma unroll
        for (int j = 0; j < 4; ++j) sacc[j] = (f32x4){0.f, 0.f, 0.f, 0.f};
        #pragma unroll
        for (int nt = 0; nt < 4; ++nt) {
            sacc[nt] = __builtin_amdgcn_mfma_f32_16x16x32_bf16(kf[nt][0], qf0, sacc[nt], 0, 0, 0);
            sacc[nt] = __builtin_amdgcn_mfma_f32_16x16x32_bf16(kf[nt][1], qf1, sacc[nt], 0, 0, 0);
        }

        // ---- P = exp(S), causal mask on the diagonal tile (no max shift)
        if (c == tile) {
            #pragma unroll
            for (int nt = 0; nt < 4; ++nt)
                #pragma unroll
                for (int r = 0; r < 4; ++r) {
                    const int keyl = nt * 16 + g * 4 + r;
                    sacc[nt][r] = (keyl > qr) ? 0.f : __expf(sacc[nt][r]);
                }
        } else {
            #pragma unroll
            for (int nt = 0; nt < 4; ++nt)
                #pragma unroll
                for (int r = 0; r < 4; ++r)
                    sacc[nt][r] = __expf(sacc[nt][r]);
        }

        // ---- per-lane l accumulation (q fixed = m per lane)
        #pragma unroll
        for (int nt = 0; nt < 4; ++nt)
            lrun += (sacc[nt][0] + sacc[nt][1]) + (sacc[nt][2] + sacc[nt][3]);

        // ---- pack P to bf16 (pairs -> v_cvt_pk_bf16_f32)
        unsigned pw0[4], pw1[4];
        #pragma unroll
        for (int s = 0; s < 4; ++s) {
            pw0[s] = packbf2(sacc[s][0], sacc[s][1]);
            pw1[s] = packbf2(sacc[s][2], sacc[s][3]);
        }

        // ---- O += P V via 16x16x16 (A-frag lane-local)
        #pragma unroll
        for (int s = 0; s < 4; ++s) {
            short4v pa;
            { unsigned u2[2] = {pw0[s], pw1[s]}; __builtin_memcpy(&pa, u2, 8); }
            #pragma unroll
            for (int nt = 0; nt < 4; ++nt)
                o[nt] = __builtin_amdgcn_mfma_f32_16x16x16bf16_1k(pa, vf[nt][s], o[nt], 0, 0, 0);
        }
    }

    // ---- final reduce of l across the 4 g-groups (q = m), write partial
    {
        float ts = lrun;
        ts += __shfl_xor(ts, 16, 64);
        ts += __shfl_xor(ts, 32, 64);
        if (lane < 16) lp[sidx * 64 + w * 16 + m] = ts;
    }
    // O C-layout: row q_local = g*4+r, col h = nt*16+m (per wave block w)
    #pragma unroll
    for (int nt = 0; nt < 4; ++nt)
        #pragma unroll
        for (int r = 0; r < 4; ++r)
            op[(size_t)sidx * 4096 + (w * 16 + g * 4 + r) * 64 + nt * 16 + m]
                = f2bf(o[nt][r]);
}

// ---------------------------------------------------------------------------
// Attention phase 2: plain sum-merge of 4 parity partials. Grid 256.
__global__ __launch_bounds__(256)
void attn_merge(const float* __restrict__ lp, const ushort_t* __restrict__ op,
                float* __restrict__ out)
{
    const int bq    = blockIdx.x;
    const int batch = bq >> 5;
    const int tile  = bq & 31;
    const int s0    = (batch * 32 + tile) * 4;

    const int t   = threadIdx.x;
    const int row = t >> 2;
    const int c16 = (t & 3) * 16;

    float l = 0.f;
    #pragma unroll
    for (int p = 0; p < 4; ++p) l += lp[(s0 + p) * 64 + row];
    const float inv = 1.f / l;

    float acc[16];
    #pragma unroll
    for (int j = 0; j < 16; ++j) acc[j] = 0.f;
    #pragma unroll
    for (int p = 0; p < 4; ++p) {
        short8 a0 = *(const short8*)(op + (size_t)(s0 + p) * 4096 + row * 64 + c16);
        short8 a1 = *(const short8*)(op + (size_t)(s0 + p) * 4096 + row * 64 + c16 + 8);
        #pragma unroll
        for (int j = 0; j < 8; ++j) {
            acc[j]     += bf2f((ushort_t)a0[j]);
            acc[j + 8] += bf2f((ushort_t)a1[j]);
        }
    }
    float* dst = out + (size_t)(batch * S + tile * 64 + row) * Hd + c16;
    #pragma unroll
    for (int j = 0; j < 16; ++j) dst[j] = acc[j] * inv;
}

// ---------------------------------------------------------------------------
extern "C" void kernel_launch(void* const* d_in, const int* in_sizes, int n_in,
                              void* d_out, int out_size, void* d_ws, size_t ws_size,
                              hipStream_t stream) {
    const float* x  = (const float*)d_in[0];
    const float* Wk = (const float*)d_in[1];
    const float* Wq = (const float*)d_in[2];
    const float* Wv = (const float*)d_in[3];
    float* out = (float*)d_out;

    ushort_t* qws  = (ushort_t*)d_ws;                      // 16384*64 bf16
    ushort_t* kws  = qws + (size_t)ROWS * Hd;
    ushort_t* vTws = kws + (size_t)ROWS * Hd;              // [8][64][2048] bf16
    ushort_t* WT   = vTws + (size_t)ROWS * Hd;             // 192*1024 bf16
    float*    lpp  = (float*)(WT + (size_t)NTOT * E);      // 1024*64 f32
    ushort_t* opp  = (ushort_t*)(lpp + 1024 * 64);         // 1024*4096 bf16

    prep_wt<<<(NTOT * E) / 256, 256, 0, stream>>>(Wk, Wq, Wv, WT);
    proj_v7<<<ROWS / 32, 256, 0, stream>>>(x, WT, qws, kws, vTws);
    attn_part<<<1024, 256, 0, stream>>>(qws, kws, vTws, lpp, opp);
    attn_merge<<<256, 256, 0, stream>>>(lpp, opp, out);
}

// Round 4
// 153.582 us; speedup vs baseline: 1.1728x; 1.1728x over previous
//
#include <hip/hip_runtime.h>
#include <hip/hip_bf16.h>

typedef unsigned short ushort_t;
typedef __attribute__((ext_vector_type(8))) short short8;   // 8 bf16 (4 VGPRs)
typedef __attribute__((ext_vector_type(4))) short short4v;  // 4 bf16 (2 VGPRs)
typedef __attribute__((ext_vector_type(4))) float f32x4;    // 4 fp32 acc

__device__ __forceinline__ float bf2f(ushort_t u) {
    unsigned int x = ((unsigned int)u) << 16;
    float f; __builtin_memcpy(&f, &x, 4); return f;
}
__device__ __forceinline__ ushort_t f2bf(float f) {
    __hip_bfloat16 h = __float2bfloat16(f);
    ushort_t u; __builtin_memcpy(&u, &h, 2); return u;
}
__device__ __forceinline__ unsigned packbf2(float a, float b) {
    return (unsigned)f2bf(a) | ((unsigned)f2bf(b) << 16);
}

constexpr int E  = 1024;
constexpr int Hd = 64;
constexpr int S  = 2048;
constexpr int ROWS = 8 * 2048;   // 16384
constexpr int NTOT = 192;
constexpr int LSTP = 72;         // proj LDS row stride (16x64 tile, 144B rows)
constexpr int LSTA = 88;         // attn LDS row stride (R1-measured layout)

// ---------------------------------------------------------------------------
// prep: WT[192][1024] bf16, rows 0-63 = Wq^T, 64-127 = Wk^T, 128-191 = Wv^T
__global__ __launch_bounds__(256)
void prep_wt(const float* __restrict__ Wk, const float* __restrict__ Wq,
             const float* __restrict__ Wv, ushort_t* __restrict__ WT)
{
    int idx = blockIdx.x * 256 + threadIdx.x;
    int n = idx >> 10;
    int kk = idx & 1023;
    const float* W = (n < 64) ? Wq : ((n < 128) ? Wk : Wv);
    int h = n & 63;
    WT[idx] = f2bf(W[kk * Hd + h]);
}

// ---------------------------------------------------------------------------
// Projection v10: 16-row blocks -> grid 1024 (4 blocks/CU, 16 waves/CU; was
// 2 blocks/CU) + 4-deep x prefetch (named regs, 4-body unroll; distance ~4
// compute phases covers HBM ~900cyc). Weights in 2 alternating reg sets,
// loaded one body ahead (L2-resident WT). One barrier per body, XS0/XS1
// rotation (writer of body j+2 is fenced from reader of body j by body j+1's
// barrier).
__global__ __launch_bounds__(256)
void proj_v10(const float* __restrict__ x, const ushort_t* __restrict__ WT,
              ushort_t* __restrict__ qo, ushort_t* __restrict__ ko,
              ushort_t* __restrict__ vTo)
{
    __shared__ alignas(16) ushort_t XS0[16][LSTP];
    __shared__ alignas(16) ushort_t XS1[16][LSTP];

    const int t    = threadIdx.x;
    const int w    = t >> 6;
    const int lane = t & 63;
    const int m    = lane & 15;
    const int g    = lane >> 4;
    const int rb   = blockIdx.x * 16;

    f32x4 accq = (f32x4){0.f, 0.f, 0.f, 0.f};
    f32x4 acck = (f32x4){0.f, 0.f, 0.f, 0.f};
    f32x4 accv = (f32x4){0.f, 0.f, 0.f, 0.f};

    const float* xptr = x + (size_t)(rb + (t >> 4)) * E + (t & 15) * 4;
    const ushort_t* wqp = WT + (size_t)(w * 16 + m) * E + g * 8;
    const ushort_t* wkp = wqp + (size_t)64 * E;
    const ushort_t* wvp = wqp + (size_t)128 * E;

    const int sr = t >> 4, sc = (t & 15) * 4;

    // 4-deep x prefetch, one float4 (16 f32-bytes) per thread per K-chunk
    float4 xP0 = *(const float4*)(xptr);
    float4 xP1 = *(const float4*)(xptr + 64);
    float4 xP2 = *(const float4*)(xptr + 128);
    float4 xP3 = *(const float4*)(xptr + 192);

    // weight sets: wA = bodies 0,2; wB = bodies 1,3
    short8 wAq[2], wAk[2], wAv[2], wBq[2], wBk[2], wBv[2];
    #pragma unroll
    for (int kt = 0; kt < 2; ++kt) {
        wAq[kt] = *(const short8*)(wqp + kt * 32);
        wAk[kt] = *(const short8*)(wkp + kt * 32);
        wAv[kt] = *(const short8*)(wvp + kt * 32);
    }

    #pragma unroll 1
    for (int cc = 0; cc < 16; cc += 4) {
        // ---------------- body 0: c = cc, XS0, weights wA
        {
            uint2 sv;
            sv.x = packbf2(xP0.x, xP0.y);
            sv.y = packbf2(xP0.z, xP0.w);
            *(uint2*)&XS0[sr][sc] = sv;
        }
        __syncthreads();
        if (cc + 4 < 16) xP0 = *(const float4*)(xptr + (cc + 4) * 64);
        {   // wB <- c = cc+1 (always < 16)
            const int k0 = (cc + 1) * 64;
            #pragma unroll
            for (int kt = 0; kt < 2; ++kt) {
                wBq[kt] = *(const short8*)(wqp + k0 + kt * 32);
                wBk[kt] = *(const short8*)(wkp + k0 + kt * 32);
                wBv[kt] = *(const short8*)(wvp + k0 + kt * 32);
            }
        }
        #pragma unroll
        for (int kt = 0; kt < 2; ++kt) {
            short8 a0 = *(const short8*)&XS0[m][kt * 32 + g * 8];
            accq = __builtin_amdgcn_mfma_f32_16x16x32_bf16(a0, wAq[kt], accq, 0, 0, 0);
            acck = __builtin_amdgcn_mfma_f32_16x16x32_bf16(a0, wAk[kt], acck, 0, 0, 0);
            accv = __builtin_amdgcn_mfma_f32_16x16x32_bf16(wAv[kt], a0, accv, 0, 0, 0);
        }

        // ---------------- body 1: c = cc+1, XS1, weights wB
        {
            uint2 sv;
            sv.x = packbf2(xP1.x, xP1.y);
            sv.y = packbf2(xP1.z, xP1.w);
            *(uint2*)&XS1[sr][sc] = sv;
        }
        __syncthreads();
        if (cc + 5 < 16) xP1 = *(const float4*)(xptr + (cc + 5) * 64);
        if (cc + 2 < 16) {   // wA <- c = cc+2
            const int k0 = (cc + 2) * 64;
            #pragma unroll
            for (int kt = 0; kt < 2; ++kt) {
                wAq[kt] = *(const short8*)(wqp + k0 + kt * 32);
                wAk[kt] = *(const short8*)(wkp + k0 + kt * 32);
                wAv[kt] = *(const short8*)(wvp + k0 + kt * 32);
            }
        }
        #pragma unroll
        for (int kt = 0; kt < 2; ++kt) {
            short8 a0 = *(const short8*)&XS1[m][kt * 32 + g * 8];
            accq = __builtin_amdgcn_mfma_f32_16x16x32_bf16(a0, wBq[kt], accq, 0, 0, 0);
            acck = __builtin_amdgcn_mfma_f32_16x16x32_bf16(a0, wBk[kt], acck, 0, 0, 0);
            accv = __builtin_amdgcn_mfma_f32_16x16x32_bf16(wBv[kt], a0, accv, 0, 0, 0);
        }

        // ---------------- body 2: c = cc+2, XS0, weights wA
        {
            uint2 sv;
            sv.x = packbf2(xP2.x, xP2.y);
            sv.y = packbf2(xP2.z, xP2.w);
            *(uint2*)&XS0[sr][sc] = sv;
        }
        __syncthreads();
        if (cc + 6 < 16) xP2 = *(const float4*)(xptr + (cc + 6) * 64);
        if (cc + 3 < 16) {   // wB <- c = cc+3
            const int k0 = (cc + 3) * 64;
            #pragma unroll
            for (int kt = 0; kt < 2; ++kt) {
                wBq[kt] = *(const short8*)(wqp + k0 + kt * 32);
                wBk[kt] = *(const short8*)(wkp + k0 + kt * 32);
                wBv[kt] = *(const short8*)(wvp + k0 + kt * 32);
            }
        }
        #pragma unroll
        for (int kt = 0; kt < 2; ++kt) {
            short8 a0 = *(const short8*)&XS0[m][kt * 32 + g * 8];
            accq = __builtin_amdgcn_mfma_f32_16x16x32_bf16(a0, wAq[kt], accq, 0, 0, 0);
            acck = __builtin_amdgcn_mfma_f32_16x16x32_bf16(a0, wAk[kt], acck, 0, 0, 0);
            accv = __builtin_amdgcn_mfma_f32_16x16x32_bf16(wAv[kt], a0, accv, 0, 0, 0);
        }

        // ---------------- body 3: c = cc+3, XS1, weights wB
        {
            uint2 sv;
            sv.x = packbf2(xP3.x, xP3.y);
            sv.y = packbf2(xP3.z, xP3.w);
            *(uint2*)&XS1[sr][sc] = sv;
        }
        __syncthreads();
        if (cc + 7 < 16) xP3 = *(const float4*)(xptr + (cc + 7) * 64);
        if (cc + 4 < 16) {   // wA <- c = cc+4 (next iteration body 0)
            const int k0 = (cc + 4) * 64;
            #pragma unroll
            for (int kt = 0; kt < 2; ++kt) {
                wAq[kt] = *(const short8*)(wqp + k0 + kt * 32);
                wAk[kt] = *(const short8*)(wkp + k0 + kt * 32);
                wAv[kt] = *(const short8*)(wvp + k0 + kt * 32);
            }
        }
        #pragma unroll
        for (int kt = 0; kt < 2; ++kt) {
            short8 a0 = *(const short8*)&XS1[m][kt * 32 + g * 8];
            accq = __builtin_amdgcn_mfma_f32_16x16x32_bf16(a0, wBq[kt], accq, 0, 0, 0);
            acck = __builtin_amdgcn_mfma_f32_16x16x32_bf16(a0, wBk[kt], acck, 0, 0, 0);
            accv = __builtin_amdgcn_mfma_f32_16x16x32_bf16(wBv[kt], a0, accv, 0, 0, 0);
        }
    }

    const int col   = w * 16 + m;
    const int batch = rb >> 11;
    const int seq0  = rb & (S - 1);
    const int orow  = rb + g * 4;
    #pragma unroll
    for (int r = 0; r < 4; ++r) {
        qo[(size_t)(orow + r) * Hd + col] = f2bf(accq[r] * 0.125f);
        ko[(size_t)(orow + r) * Hd + col] = f2bf(acck[r]);
    }
    #pragma unroll
    for (int r = 0; r < 4; ++r) {
        const int h = w * 16 + g * 4 + r;
        vTo[(size_t)batch * Hd * S + (size_t)h * S + seq0 + m] = f2bf(accv[r]);
    }
}

// ---------------------------------------------------------------------------
// Attention v10 (revert to R1-measured version): LDS-staged K/V with
// coalesced uint4 loads, swapped-operand QK^T, lane-local PV via 16x16x16.
__global__ __launch_bounds__(256)
void attn_part(const ushort_t* __restrict__ q, const ushort_t* __restrict__ k,
               const ushort_t* __restrict__ vT,
               float* __restrict__ lp, ushort_t* __restrict__ op)
{
    const int bi     = blockIdx.x;
    const int parity = bi & 3;
    const int pr     = bi >> 2;
    const int batch  = pr & 7;
    const int tile   = 31 - (pr >> 3);   // longest-first
    const int qs0    = tile * 64;
    const int sidx   = (batch * 32 + tile) * 4 + parity;

    const ushort_t* kb  = k  + (size_t)batch * S * Hd;
    const ushort_t* vTb = vT + (size_t)batch * Hd * S;

    const int t    = threadIdx.x;
    const int w    = t >> 6;
    const int lane = t & 63;
    const int m    = lane & 15;
    const int g    = lane >> 4;

    __shared__ alignas(16) ushort_t KS [64][LSTA];
    __shared__ alignas(16) ushort_t VTS[64][LSTA];

    const ushort_t* qrow = q + (size_t)(batch * S + qs0 + w * 16 + m) * Hd;
    short8 qf0 = *(const short8*)(qrow + g * 8);
    short8 qf1 = *(const short8*)(qrow + 32 + g * 8);

    f32x4 o[4];
    #pragma unroll
    for (int j = 0; j < 4; ++j) o[j] = (f32x4){0.f, 0.f, 0.f, 0.f};
    float lrun = 0.f;
    const int qr = w * 16 + m;   // q row within the 64-row block (mask)

    const int r1 = t >> 3, c16 = (t & 7) * 8;
    uint4 pk0, pk1, pv0, pv1;

    int c = parity;
    if (c <= tile) {
        const int key0 = c * 64;
        const ushort_t* kt_base = kb + (size_t)key0 * Hd;   // 8 KB flat
        pk0 = *(const uint4*)(kt_base + t * 8);
        pk1 = *(const uint4*)(kt_base + (t + 256) * 8);
        pv0 = *(const uint4*)(vTb + (size_t)r1 * S + key0 + c16);
        pv1 = *(const uint4*)(vTb + (size_t)(r1 + 32) * S + key0 + c16);
    }

    for (; c <= tile; c += 4) {
        *(uint4*)&KS [r1][c16]       = pk0;
        *(uint4*)&KS [r1 + 32][c16]  = pk1;
        *(uint4*)&VTS[r1][c16]       = pv0;
        *(uint4*)&VTS[r1 + 32][c16]  = pv1;
        __syncthreads();

        if (c + 4 <= tile) {
            const int key0n = (c + 4) * 64;
            const ushort_t* kt_base = kb + (size_t)key0n * Hd;
            pk0 = *(const uint4*)(kt_base + t * 8);
            pk1 = *(const uint4*)(kt_base + (t + 256) * 8);
            pv0 = *(const uint4*)(vTb + (size_t)r1 * S + key0n + c16);
            pv1 = *(const uint4*)(vTb + (size_t)(r1 + 32) * S + key0n + c16);
        }

        // ---- S^T = K Q^T: sacc[nt][r] = S[q = w*16+m][key = nt*16+g*4+r]
        f32x4 sacc[4];
        #pragma unroll
        for (int j = 0; j < 4; ++j) sacc[j] = (f32x4){0.f, 0.f, 0.f, 0.f};
        #pragma unroll
        for (int nt = 0; nt < 4; ++nt) {
            short8 b0 = *(const short8*)&KS[nt * 16 + m][g * 8];
            short8 b1 = *(const short8*)&KS[nt * 16 + m][32 + g * 8];
            sacc[nt] = __builtin_amdgcn_mfma_f32_16x16x32_bf16(b0, qf0, sacc[nt], 0, 0, 0);
            sacc[nt] = __builtin_amdgcn_mfma_f32_16x16x32_bf16(b1, qf1, sacc[nt], 0, 0, 0);
        }

        // ---- P = exp(S), causal mask on the diagonal tile (no max shift)
        if (c == tile) {
            #pragma unroll
            for (int nt = 0; nt < 4; ++nt)
                #pragma unroll
                for (int r = 0; r < 4; ++r) {
                    const int keyl = nt * 16 + g * 4 + r;
                    sacc[nt][r] = (keyl > qr) ? 0.f : __expf(sacc[nt][r]);
                }
        } else {
            #pragma unroll
            for (int nt = 0; nt < 4; ++nt)
                #pragma unroll
                for (int r = 0; r < 4; ++r)
                    sacc[nt][r] = __expf(sacc[nt][r]);
        }

        // ---- per-lane l accumulation (q fixed = m per lane)
        #pragma unroll
        for (int nt = 0; nt < 4; ++nt)
            lrun += (sacc[nt][0] + sacc[nt][1]) + (sacc[nt][2] + sacc[nt][3]);

        // ---- pack P to bf16 (pairs -> v_cvt_pk_bf16_f32)
        unsigned pw0[4], pw1[4];
        #pragma unroll
        for (int s = 0; s < 4; ++s) {
            pw0[s] = packbf2(sacc[s][0], sacc[s][1]);
            pw1[s] = packbf2(sacc[s][2], sacc[s][3]);
        }

        // ---- O += P V via 16x16x16 (A-frag lane-local: no LDS, no shuffle)
        #pragma unroll
        for (int s = 0; s < 4; ++s) {
            short4v pa;
            { unsigned u2[2] = {pw0[s], pw1[s]}; __builtin_memcpy(&pa, u2, 8); }
            #pragma unroll
            for (int nt = 0; nt < 4; ++nt) {
                short4v vb = *(const short4v*)&VTS[nt * 16 + m][s * 16 + g * 4];
                o[nt] = __builtin_amdgcn_mfma_f32_16x16x16bf16_1k(pa, vb, o[nt], 0, 0, 0);
            }
        }
        __syncthreads();
    }

    // ---- final reduce of l across the 4 g-groups (q = m), write partial
    {
        float ts = lrun;
        ts += __shfl_xor(ts, 16, 64);
        ts += __shfl_xor(ts, 32, 64);
        if (lane < 16) lp[sidx * 64 + w * 16 + m] = ts;
    }
    #pragma unroll
    for (int nt = 0; nt < 4; ++nt)
        #pragma unroll
        for (int r = 0; r < 4; ++r)
            op[(size_t)sidx * 4096 + (w * 16 + g * 4 + r) * 64 + nt * 16 + m]
                = f2bf(o[nt][r]);
}

// ---------------------------------------------------------------------------
// Attention phase 2: plain sum-merge of 4 parity partials. Grid 256.
__global__ __launch_bounds__(256)
void attn_merge(const float* __restrict__ lp, const ushort_t* __restrict__ op,
                float* __restrict__ out)
{
    const int bq    = blockIdx.x;
    const int batch = bq >> 5;
    const int tile  = bq & 31;
    const int s0    = (batch * 32 + tile) * 4;

    const int t   = threadIdx.x;
    const int row = t >> 2;
    const int c16 = (t & 3) * 16;

    float l = 0.f;
    #pragma unroll
    for (int p = 0; p < 4; ++p) l += lp[(s0 + p) * 64 + row];
    const float inv = 1.f / l;

    float acc[16];
    #pragma unroll
    for (int j = 0; j < 16; ++j) acc[j] = 0.f;
    #pragma unroll
    for (int p = 0; p < 4; ++p) {
        short8 a0 = *(const short8*)(op + (size_t)(s0 + p) * 4096 + row * 64 + c16);
        short8 a1 = *(const short8*)(op + (size_t)(s0 + p) * 4096 + row * 64 + c16 + 8);
        #pragma unroll
        for (int j = 0; j < 8; ++j) {
            acc[j]     += bf2f((ushort_t)a0[j]);
            acc[j + 8] += bf2f((ushort_t)a1[j]);
        }
    }
    float* dst = out + (size_t)(batch * S + tile * 64 + row) * Hd + c16;
    #pragma unroll
    for (int j = 0; j < 16; ++j) dst[j] = acc[j] * inv;
}

// ---------------------------------------------------------------------------
extern "C" void kernel_launch(void* const* d_in, const int* in_sizes, int n_in,
                              void* d_out, int out_size, void* d_ws, size_t ws_size,
                              hipStream_t stream) {
    const float* x  = (const float*)d_in[0];
    const float* Wk = (const float*)d_in[1];
    const float* Wq = (const float*)d_in[2];
    const float* Wv = (const float*)d_in[3];
    float* out = (float*)d_out;

    ushort_t* qws  = (ushort_t*)d_ws;                      // 16384*64 bf16
    ushort_t* kws  = qws + (size_t)ROWS * Hd;
    ushort_t* vTws = kws + (size_t)ROWS * Hd;              // [8][64][2048] bf16
    ushort_t* WT   = vTws + (size_t)ROWS * Hd;             // 192*1024 bf16
    float*    lpp  = (float*)(WT + (size_t)NTOT * E);      // 1024*64 f32
    ushort_t* opp  = (ushort_t*)(lpp + 1024 * 64);         // 1024*4096 bf16

    prep_wt<<<(NTOT * E) / 256, 256, 0, stream>>>(Wk, Wq, Wv, WT);
    proj_v10<<<ROWS / 16, 256, 0, stream>>>(x, WT, qws, kws, vTws);
    attn_part<<<1024, 256, 0, stream>>>(qws, kws, vTws, lpp, opp);
    attn_merge<<<256, 256, 0, stream>>>(lpp, opp, out);
}

// Round 6
// 132.338 us; speedup vs baseline: 1.3611x; 1.1605x over previous
//
#include <hip/hip_runtime.h>
#include <hip/hip_bf16.h>

typedef unsigned short ushort_t;
typedef __attribute__((ext_vector_type(8))) short short8;   // 8 bf16 (4 VGPRs)
typedef __attribute__((ext_vector_type(4))) short short4v;  // 4 bf16 (2 VGPRs)
typedef __attribute__((ext_vector_type(4))) float f32x4;    // 4 fp32 acc

__device__ __forceinline__ float bf2f(ushort_t u) {
    unsigned int x = ((unsigned int)u) << 16;
    float f; __builtin_memcpy(&f, &x, 4); return f;
}
__device__ __forceinline__ ushort_t f2bf(float f) {
    __hip_bfloat16 h = __float2bfloat16(f);
    ushort_t u; __builtin_memcpy(&u, &h, 2); return u;
}
__device__ __forceinline__ unsigned packbf2(float a, float b) {
    return (unsigned)f2bf(a) | ((unsigned)f2bf(b) << 16);
}

// Direct-to-LDS DMA, 16B per lane. No dest VGPR -> the compiler cannot sink
// it (the fix for the reg-prefetch schemes it deleted in R2/R4).
__device__ __forceinline__ void gload16(const void* g, void* l) {
    __builtin_amdgcn_global_load_lds(
        (const __attribute__((address_space(1))) unsigned int*)g,
        (__attribute__((address_space(3))) unsigned int*)l, 16, 0, 0);
}

constexpr int E  = 1024;
constexpr int Hd = 64;
constexpr int S  = 2048;
constexpr int ROWS = 8 * 2048;   // 16384
constexpr int NTOT = 192;
constexpr int LSTA = 88;         // attn LDS row stride (R1-measured layout)

// ---------------------------------------------------------------------------
// prep: WT[192][1024] bf16, rows 0-63 = Wq^T, 64-127 = Wk^T, 128-191 = Wv^T
__global__ __launch_bounds__(256)
void prep_wt(const float* __restrict__ Wk, const float* __restrict__ Wq,
             const float* __restrict__ Wv, ushort_t* __restrict__ WT)
{
    int idx = blockIdx.x * 256 + threadIdx.x;
    int n = idx >> 10;
    int kk = idx & 1023;
    const float* W = (n < 64) ? Wq : ((n < 128) ? Wk : Wv);
    int h = n & 63;
    WT[idx] = f2bf(W[kk * Hd + h]);
}

// ---------------------------------------------------------------------------
// Projection v11: global_load_lds staging for BOTH x (f32) and per-body
// weights (bf16), double-buffered, one barrier per body (T3 2-phase:
// stage(next) -> compute(current) -> barrier; the barrier's implicit
// vmcnt(0) drain lands after a full compute phase of cover).
// Swizzle per rule #21: LDS linear dest, global source pre-swizzled with
// U ^= (row&7) on 16B units, reads apply the same XOR -> uniform bank quads.
// 32-row blocks, grid 512; LDS 64KB -> 2 blocks/CU.
__global__ __launch_bounds__(256, 2)
void proj_v11(const float* __restrict__ x, const ushort_t* __restrict__ WT,
              ushort_t* __restrict__ qo, ushort_t* __restrict__ ko,
              ushort_t* __restrict__ vTo)
{
    __shared__ alignas(16) float    XS[2][32 * 64];    // 8KB x-tile  x2
    __shared__ alignas(16) ushort_t WS[2][192 * 64];   // 24KB w-tile x2

    const int t    = threadIdx.x;
    const int w    = t >> 6;
    const int lane = t & 63;
    const int m    = lane & 15;
    const int g    = lane >> 4;
    const int rl   = m & 7;          // row-swizzle key (row&7 == m&7 everywhere)
    const int rb   = blockIdx.x * 32;

    f32x4 accq[2], acck[2], accv[2];
    #pragma unroll
    for (int j = 0; j < 2; ++j) {
        accq[j] = (f32x4){0.f, 0.f, 0.f, 0.f};
        acck[j] = (f32x4){0.f, 0.f, 0.f, 0.f};
        accv[j] = (f32x4){0.f, 0.f, 0.f, 0.f};
    }

    // ---- staging source pointers (inverse-swizzled): unit L holds tile unit
    // (row = L/units_per_row, U = (L%upr) ^ (row&7)).
    const int xrow0 = t >> 4;                 // x issue 0: rows 0..15
    const int xrow1 = (256 + t) >> 4;         // x issue 1: rows 16..31
    const int xU0   = (t & 15) ^ (xrow0 & 7);
    const int xU1   = (t & 15) ^ (xrow1 & 7);
    const float* xs0 = x + (size_t)(rb + xrow0) * E + xU0 * 4;
    const float* xs1 = x + (size_t)(rb + xrow1) * E + xU1 * 4;

    const ushort_t* wsrc[6];
    #pragma unroll
    for (int j = 0; j < 6; ++j) {
        const int L    = j * 256 + t;
        const int wrow = L >> 3;
        const int wU   = (L & 7) ^ (wrow & 7);
        wsrc[j] = WT + (size_t)wrow * E + wU * 8;
    }

    // ---- fragment LDS offsets (lane-constant, element units)
    int xiA[2][2], xiB[2][2];                 // [h][kt] f32 index
    #pragma unroll
    for (int h = 0; h < 2; ++h)
        #pragma unroll
        for (int kt = 0; kt < 2; ++kt) {
            const int row = h * 16 + m;
            const int U   = kt * 8 + 2 * g;
            xiA[h][kt] = (row * 16 + (U ^ rl)) * 4;
            xiB[h][kt] = (row * 16 + ((U + 1) ^ rl)) * 4;
        }
    int wiq[2], wik[2], wiv[2];               // [kt] ushort index
    #pragma unroll
    for (int kt = 0; kt < 2; ++kt) {
        const int U = kt * 4 + g;
        wiq[kt] = ((      w * 16 + m) * 8 + (U ^ rl)) * 8;
        wik[kt] = ((64  + w * 16 + m) * 8 + (U ^ rl)) * 8;
        wiv[kt] = ((128 + w * 16 + m) * 8 + (U ^ rl)) * 8;
    }

    auto STAGE = [&](int buf, int c) {
        const int k0 = c * 64;
        char* xb = (char*)&XS[buf][0];
        char* wb = (char*)&WS[buf][0];
        gload16(xs0 + k0, xb + (size_t)t * 16);
        gload16(xs1 + k0, xb + (size_t)(256 + t) * 16);
        #pragma unroll
        for (int j = 0; j < 6; ++j)
            gload16(wsrc[j] + k0, wb + (size_t)(j * 256 + t) * 16);
    };

    auto COMPUTE = [&](int buf) {
        #pragma unroll
        for (int kt = 0; kt < 2; ++kt) {
            short8 fq = *(const short8*)&WS[buf][wiq[kt]];
            short8 fk = *(const short8*)&WS[buf][wik[kt]];
            short8 fv = *(const short8*)&WS[buf][wiv[kt]];
            #pragma unroll
            for (int h = 0; h < 2; ++h) {
                float4 A = *(const float4*)&XS[buf][xiA[h][kt]];
                float4 B = *(const float4*)&XS[buf][xiB[h][kt]];
                short8 a;
                {
                    unsigned u4[4];
                    u4[0] = packbf2(A.x, A.y);
                    u4[1] = packbf2(A.z, A.w);
                    u4[2] = packbf2(B.x, B.y);
                    u4[3] = packbf2(B.z, B.w);
                    __builtin_memcpy(&a, u4, 16);
                }
                accq[h] = __builtin_amdgcn_mfma_f32_16x16x32_bf16(a, fq, accq[h], 0, 0, 0);
                acck[h] = __builtin_amdgcn_mfma_f32_16x16x32_bf16(a, fk, acck[h], 0, 0, 0);
                accv[h] = __builtin_amdgcn_mfma_f32_16x16x32_bf16(fv, a, accv[h], 0, 0, 0);
            }
        }
    };

    STAGE(0, 0);
    __syncthreads();                          // implicit vmcnt(0) drain

    #pragma unroll 1
    for (int cc = 0; cc < 16; cc += 2) {
        STAGE(1, cc + 1);                     // cc+1 <= 15 always
        COMPUTE(0);
        __syncthreads();
        if (cc + 2 < 16) STAGE(0, cc + 2);
        COMPUTE(1);
        __syncthreads();
    }

    const int col   = w * 16 + m;
    const int batch = rb >> 11;
    const int seq0  = rb & (S - 1);
    #pragma unroll
    for (int mt = 0; mt < 2; ++mt) {
        const int orow = rb + mt * 16 + g * 4;
        #pragma unroll
        for (int r = 0; r < 4; ++r) {
            qo[(size_t)(orow + r) * Hd + col] = f2bf(accq[mt][r] * 0.125f);
            ko[(size_t)(orow + r) * Hd + col] = f2bf(acck[mt][r]);
        }
    }
    #pragma unroll
    for (int ns = 0; ns < 2; ++ns)
        #pragma unroll
        for (int r = 0; r < 4; ++r) {
            const int h = w * 16 + g * 4 + r;
            vTo[(size_t)batch * Hd * S + (size_t)h * S + seq0 + ns * 16 + m]
                = f2bf(accv[ns][r]);
        }
}

// ---------------------------------------------------------------------------
// Attention v10 (R1-measured version, untouched): LDS-staged K/V with
// coalesced uint4 loads, swapped-operand QK^T, lane-local PV via 16x16x16.
__global__ __launch_bounds__(256)
void attn_part(const ushort_t* __restrict__ q, const ushort_t* __restrict__ k,
               const ushort_t* __restrict__ vT,
               float* __restrict__ lp, ushort_t* __restrict__ op)
{
    const int bi     = blockIdx.x;
    const int parity = bi & 3;
    const int pr     = bi >> 2;
    const int batch  = pr & 7;
    const int tile   = 31 - (pr >> 3);   // longest-first
    const int qs0    = tile * 64;
    const int sidx   = (batch * 32 + tile) * 4 + parity;

    const ushort_t* kb  = k  + (size_t)batch * S * Hd;
    const ushort_t* vTb = vT + (size_t)batch * Hd * S;

    const int t    = threadIdx.x;
    const int w    = t >> 6;
    const int lane = t & 63;
    const int m    = lane & 15;
    const int g    = lane >> 4;

    __shared__ alignas(16) ushort_t KS [64][LSTA];
    __shared__ alignas(16) ushort_t VTS[64][LSTA];

    const ushort_t* qrow = q + (size_t)(batch * S + qs0 + w * 16 + m) * Hd;
    short8 qf0 = *(const short8*)(qrow + g * 8);
    short8 qf1 = *(const short8*)(qrow + 32 + g * 8);

    f32x4 o[4];
    #pragma unroll
    for (int j = 0; j < 4; ++j) o[j] = (f32x4){0.f, 0.f, 0.f, 0.f};
    float lrun = 0.f;
    const int qr = w * 16 + m;   // q row within the 64-row block (mask)

    const int r1 = t >> 3, c16 = (t & 7) * 8;
    uint4 pk0, pk1, pv0, pv1;

    int c = parity;
    if (c <= tile) {
        const int key0 = c * 64;
        const ushort_t* kt_base = kb + (size_t)key0 * Hd;   // 8 KB flat
        pk0 = *(const uint4*)(kt_base + t * 8);
        pk1 = *(const uint4*)(kt_base + (t + 256) * 8);
        pv0 = *(const uint4*)(vTb + (size_t)r1 * S + key0 + c16);
        pv1 = *(const uint4*)(vTb + (size_t)(r1 + 32) * S + key0 + c16);
    }

    for (; c <= tile; c += 4) {
        *(uint4*)&KS [r1][c16]       = pk0;
        *(uint4*)&KS [r1 + 32][c16]  = pk1;
        *(uint4*)&VTS[r1][c16]       = pv0;
        *(uint4*)&VTS[r1 + 32][c16]  = pv1;
        __syncthreads();

        if (c + 4 <= tile) {
            const int key0n = (c + 4) * 64;
            const ushort_t* kt_base = kb + (size_t)key0n * Hd;
            pk0 = *(const uint4*)(kt_base + t * 8);
            pk1 = *(const uint4*)(kt_base + (t + 256) * 8);
            pv0 = *(const uint4*)(vTb + (size_t)r1 * S + key0n + c16);
            pv1 = *(const uint4*)(vTb + (size_t)(r1 + 32) * S + key0n + c16);
        }

        // ---- S^T = K Q^T: sacc[nt][r] = S[q = w*16+m][key = nt*16+g*4+r]
        f32x4 sacc[4];
        #pragma unroll
        for (int j = 0; j < 4; ++j) sacc[j] = (f32x4){0.f, 0.f, 0.f, 0.f};
        #pragma unroll
        for (int nt = 0; nt < 4; ++nt) {
            short8 b0 = *(const short8*)&KS[nt * 16 + m][g * 8];
            short8 b1 = *(const short8*)&KS[nt * 16 + m][32 + g * 8];
            sacc[nt] = __builtin_amdgcn_mfma_f32_16x16x32_bf16(b0, qf0, sacc[nt], 0, 0, 0);
            sacc[nt] = __builtin_amdgcn_mfma_f32_16x16x32_bf16(b1, qf1, sacc[nt], 0, 0, 0);
        }

        // ---- P = exp(S), causal mask on the diagonal tile (no max shift)
        if (c == tile) {
            #pragma unroll
            for (int nt = 0; nt < 4; ++nt)
                #pragma unroll
                for (int r = 0; r < 4; ++r) {
                    const int keyl = nt * 16 + g * 4 + r;
                    sacc[nt][r] = (keyl > qr) ? 0.f : __expf(sacc[nt][r]);
                }
        } else {
            #pragma unroll
            for (int nt = 0; nt < 4; ++nt)
                #pragma unroll
                for (int r = 0; r < 4; ++r)
                    sacc[nt][r] = __expf(sacc[nt][r]);
        }

        // ---- per-lane l accumulation (q fixed = m per lane)
        #pragma unroll
        for (int nt = 0; nt < 4; ++nt)
            lrun += (sacc[nt][0] + sacc[nt][1]) + (sacc[nt][2] + sacc[nt][3]);

        // ---- pack P to bf16 (pairs -> v_cvt_pk_bf16_f32)
        unsigned pw0[4], pw1[4];
        #pragma unroll
        for (int s = 0; s < 4; ++s) {
            pw0[s] = packbf2(sacc[s][0], sacc[s][1]);
            pw1[s] = packbf2(sacc[s][2], sacc[s][3]);
        }

        // ---- O += P V via 16x16x16 (A-frag lane-local: no LDS, no shuffle)
        #pragma unroll
        for (int s = 0; s < 4; ++s) {
            short4v pa;
            { unsigned u2[2] = {pw0[s], pw1[s]}; __builtin_memcpy(&pa, u2, 8); }
            #pragma unroll
            for (int nt = 0; nt < 4; ++nt) {
                short4v vb = *(const short4v*)&VTS[nt * 16 + m][s * 16 + g * 4];
                o[nt] = __builtin_amdgcn_mfma_f32_16x16x16bf16_1k(pa, vb, o[nt], 0, 0, 0);
            }
        }
        __syncthreads();
    }

    // ---- final reduce of l across the 4 g-groups (q = m), write partial
    {
        float ts = lrun;
        ts += __shfl_xor(ts, 16, 64);
        ts += __shfl_xor(ts, 32, 64);
        if (lane < 16) lp[sidx * 64 + w * 16 + m] = ts;
    }
    #pragma unroll
    for (int nt = 0; nt < 4; ++nt)
        #pragma unroll
        for (int r = 0; r < 4; ++r)
            op[(size_t)sidx * 4096 + (w * 16 + g * 4 + r) * 64 + nt * 16 + m]
                = f2bf(o[nt][r]);
}

// ---------------------------------------------------------------------------
// Attention phase 2: plain sum-merge of 4 parity partials. Grid 256.
__global__ __launch_bounds__(256)
void attn_merge(const float* __restrict__ lp, const ushort_t* __restrict__ op,
                float* __restrict__ out)
{
    const int bq    = blockIdx.x;
    const int batch = bq >> 5;
    const int tile  = bq & 31;
    const int s0    = (batch * 32 + tile) * 4;

    const int t   = threadIdx.x;
    const int row = t >> 2;
    const int c16 = (t & 3) * 16;

    float l = 0.f;
    #pragma unroll
    for (int p = 0; p < 4; ++p) l += lp[(s0 + p) * 64 + row];
    const float inv = 1.f / l;

    float acc[16];
    #pragma unroll
    for (int j = 0; j < 16; ++j) acc[j] = 0.f;
    #pragma unroll
    for (int p = 0; p < 4; ++p) {
        short8 a0 = *(const short8*)(op + (size_t)(s0 + p) * 4096 + row * 64 + c16);
        short8 a1 = *(const short8*)(op + (size_t)(s0 + p) * 4096 + row * 64 + c16 + 8);
        #pragma unroll
        for (int j = 0; j < 8; ++j) {
            acc[j]     += bf2f((ushort_t)a0[j]);
            acc[j + 8] += bf2f((ushort_t)a1[j]);
        }
    }
    float* dst = out + (size_t)(batch * S + tile * 64 + row) * Hd + c16;
    #pragma unroll
    for (int j = 0; j < 16; ++j) dst[j] = acc[j] * inv;
}

// ---------------------------------------------------------------------------
extern "C" void kernel_launch(void* const* d_in, const int* in_sizes, int n_in,
                              void* d_out, int out_size, void* d_ws, size_t ws_size,
                              hipStream_t stream) {
    const float* x  = (const float*)d_in[0];
    const float* Wk = (const float*)d_in[1];
    const float* Wq = (const float*)d_in[2];
    const float* Wv = (const float*)d_in[3];
    float* out = (float*)d_out;

    ushort_t* qws  = (ushort_t*)d_ws;                      // 16384*64 bf16
    ushort_t* kws  = qws + (size_t)ROWS * Hd;
    ushort_t* vTws = kws + (size_t)ROWS * Hd;              // [8][64][2048] bf16
    ushort_t* WT   = vTws + (size_t)ROWS * Hd;             // 192*1024 bf16
    float*    lpp  = (float*)(WT + (size_t)NTOT * E);      // 1024*64 f32
    ushort_t* opp  = (ushort_t*)(lpp + 1024 * 64);         // 1024*4096 bf16

    prep_wt<<<(NTOT * E) / 256, 256, 0, stream>>>(Wk, Wq, Wv, WT);
    proj_v11<<<ROWS / 32, 256, 0, stream>>>(x, WT, qws, kws, vTws);
    attn_part<<<1024, 256, 0, stream>>>(qws, kws, vTws, lpp, opp);
    attn_merge<<<256, 256, 0, stream>>>(lpp, opp, out);
}

// Round 7
// 128.999 us; speedup vs baseline: 1.3963x; 1.0259x over previous
//
#include <hip/hip_runtime.h>
#include <hip/hip_bf16.h>

typedef unsigned short ushort_t;
typedef __attribute__((ext_vector_type(8))) short short8;   // 8 bf16 (4 VGPRs)
typedef __attribute__((ext_vector_type(4))) short short4v;  // 4 bf16 (2 VGPRs)
typedef __attribute__((ext_vector_type(4))) float f32x4;    // 4 fp32 acc

__device__ __forceinline__ float bf2f(ushort_t u) {
    unsigned int x = ((unsigned int)u) << 16;
    float f; __builtin_memcpy(&f, &x, 4); return f;
}
__device__ __forceinline__ ushort_t f2bf(float f) {
    __hip_bfloat16 h = __float2bfloat16(f);
    ushort_t u; __builtin_memcpy(&u, &h, 2); return u;
}
__device__ __forceinline__ unsigned packbf2(float a, float b) {
    return (unsigned)f2bf(a) | ((unsigned)f2bf(b) << 16);
}

// Direct-to-LDS DMA, 16B per lane. No dest VGPR -> the compiler cannot sink it.
__device__ __forceinline__ void gload16(const void* g, void* l) {
    __builtin_amdgcn_global_load_lds(
        (const __attribute__((address_space(1))) unsigned int*)g,
        (__attribute__((address_space(3))) unsigned int*)l, 16, 0, 0);
}

constexpr int E  = 1024;
constexpr int Hd = 64;
constexpr int S  = 2048;
constexpr int ROWS = 8 * 2048;   // 16384
constexpr int NTOT = 192;
constexpr int LSTA = 88;         // attn LDS row stride (R1-measured layout)
constexpr int BM   = 64;         // proj rows per block

// ---------------------------------------------------------------------------
// prep: WT[192][1024] bf16, rows 0-63 = Wq^T, 64-127 = Wk^T, 128-191 = Wv^T
__global__ __launch_bounds__(256)
void prep_wt(const float* __restrict__ Wk, const float* __restrict__ Wq,
             const float* __restrict__ Wv, ushort_t* __restrict__ WT)
{
    int idx = blockIdx.x * 256 + threadIdx.x;
    int n = idx >> 10;
    int kk = idx & 1023;
    const float* W = (n < 64) ? Wq : ((n < 128) ? Wk : Wv);
    int h = n & 63;
    WT[idx] = f2bf(W[kk * Hd + h]);
}

// ---------------------------------------------------------------------------
// Projection v12: 64 rows/block (grid 256, 512 thr) -> weight restaging
// halves to 98 MB; 3-buffer COUNTED-vmcnt pipeline (T3+T4): 5 gload16/thread/
// body, steady-state `s_waitcnt vmcnt(10)` (never 0) -> loads for body i+3
// fly across bodies i+1,i+2 (~2x service time >> 900cyc HBM latency).
// The v11 per-body vmcnt(0) drain (16 x ~2us device-wide service steps = the
// measured ~34us) is gone. Same verified XOR swizzle (key = row&7 = m&7; all
// row offsets are multiples of 16). LDS 120 KB -> 1 block/CU, 8 waves.
__global__ __launch_bounds__(512, 2)
void proj_v12(const float* __restrict__ x, const ushort_t* __restrict__ WT,
              ushort_t* __restrict__ qo, ushort_t* __restrict__ ko,
              ushort_t* __restrict__ vTo)
{
    __shared__ alignas(16) float    XS[3][BM * 64];    // 16KB x-tile   x3
    __shared__ alignas(16) ushort_t WS[3][192 * 64];   // 24KB w-tile   x3

    const int t    = threadIdx.x;        // 0..511
    const int w    = t >> 6;             // 0..7
    const int lane = t & 63;
    const int m    = lane & 15;
    const int g    = lane >> 4;
    const int rl   = m & 7;              // swizzle key (row&7 == m&7 at all reads)
    const int cg   = w & 3;              // col-group (16 cols of 64)
    const int mh   = w >> 2;             // row-half  (32 rows of 64)
    const int rb   = blockIdx.x * BM;

    f32x4 accq[2], acck[2], accv[2];
    #pragma unroll
    for (int j = 0; j < 2; ++j) {
        accq[j] = (f32x4){0.f, 0.f, 0.f, 0.f};
        acck[j] = (f32x4){0.f, 0.f, 0.f, 0.f};
        accv[j] = (f32x4){0.f, 0.f, 0.f, 0.f};
    }

    // ---- staging sources (inverse-swizzled; unit = 16B)
    const int xr0 = t >> 4,         xu0 = (t & 15) ^ (xr0 & 7);
    const int xr1 = (t + 512) >> 4, xu1 = (t & 15) ^ (xr1 & 7);
    const float* xsrc0 = x + (size_t)(rb + xr0) * E + xu0 * 4;
    const float* xsrc1 = x + (size_t)(rb + xr1) * E + xu1 * 4;

    const ushort_t* wsrc[3];
    #pragma unroll
    for (int j = 0; j < 3; ++j) {
        const int L  = j * 512 + t;
        const int wr = L >> 3;
        const int wu = (L & 7) ^ (wr & 7);
        wsrc[j] = WT + (size_t)wr * E + wu * 8;
    }

    // ---- fragment LDS offsets (lane constants)
    int xiA[2][2], xiB[2][2];                 // [h][kt], f32 index
    #pragma unroll
    for (int h = 0; h < 2; ++h)
        #pragma unroll
        for (int kt = 0; kt < 2; ++kt) {
            const int row = mh * 32 + h * 16 + m;
            const int U   = kt * 8 + 2 * g;
            xiA[h][kt] = (row * 16 + (U ^ rl)) * 4;
            xiB[h][kt] = (row * 16 + ((U + 1) ^ rl)) * 4;
        }
    int wiq[2], wik[2], wiv[2];               // [kt], ushort index
    #pragma unroll
    for (int kt = 0; kt < 2; ++kt) {
        const int U = kt * 4 + g;
        wiq[kt] = ((      cg * 16 + m) * 8 + (U ^ rl)) * 8;
        wik[kt] = ((64  + cg * 16 + m) * 8 + (U ^ rl)) * 8;
        wiv[kt] = ((128 + cg * 16 + m) * 8 + (U ^ rl)) * 8;
    }

    auto STAGE = [&](int buf, int c) {        // 5 gload16 / thread
        const int k0 = c * 64;
        char* xb = (char*)&XS[buf][0];
        char* wb = (char*)&WS[buf][0];
        gload16(xsrc0 + k0, xb + (size_t)t * 16);
        gload16(xsrc1 + k0, xb + (size_t)(t + 512) * 16);
        #pragma unroll
        for (int j = 0; j < 3; ++j)
            gload16(wsrc[j] + k0, wb + (size_t)(j * 512 + t) * 16);
    };

    auto COMPUTE = [&](int buf) {
        #pragma unroll
        for (int kt = 0; kt < 2; ++kt) {
            short8 fq = *(const short8*)&WS[buf][wiq[kt]];
            short8 fk = *(const short8*)&WS[buf][wik[kt]];
            short8 fv = *(const short8*)&WS[buf][wiv[kt]];
            #pragma unroll
            for (int h = 0; h < 2; ++h) {
                float4 A = *(const float4*)&XS[buf][xiA[h][kt]];
                float4 B = *(const float4*)&XS[buf][xiB[h][kt]];
                short8 a;
                {
                    unsigned u4[4];
                    u4[0] = packbf2(A.x, A.y);
                    u4[1] = packbf2(A.z, A.w);
                    u4[2] = packbf2(B.x, B.y);
                    u4[3] = packbf2(B.z, B.w);
                    __builtin_memcpy(&a, u4, 16);
                }
                accq[h] = __builtin_amdgcn_mfma_f32_16x16x32_bf16(a, fq, accq[h], 0, 0, 0);
                acck[h] = __builtin_amdgcn_mfma_f32_16x16x32_bf16(a, fk, acck[h], 0, 0, 0);
                accv[h] = __builtin_amdgcn_mfma_f32_16x16x32_bf16(fv, a, accv[h], 0, 0, 0);
            }
        }
    };

    // ---- prologue: 3 bodies in flight (15 loads/thread outstanding)
    STAGE(0, 0);
    STAGE(1, 1);
    STAGE(2, 2);

    // ---- main loop: counted waits, never vmcnt(0) until the tail.
    // Ledger: before body i's wait, outstanding = bodies i,i+1,i+2 (15);
    // vmcnt(10) drains exactly body i's 5. stage(i+3) reuses buf[i%3] only
    // after barrier2 confirms all waves finished reading it.
    #pragma unroll
    for (int i = 0; i < 16; ++i) {
        if (i < 14)       { asm volatile("s_waitcnt vmcnt(10)" ::: "memory"); }
        else if (i == 14) { asm volatile("s_waitcnt vmcnt(5)"  ::: "memory"); }
        else              { asm volatile("s_waitcnt vmcnt(0)"  ::: "memory"); }
        __builtin_amdgcn_sched_barrier(0);
        __builtin_amdgcn_s_barrier();
        COMPUTE(i % 3);
        __builtin_amdgcn_s_barrier();
        if (i + 3 < 16) STAGE(i % 3, i + 3);
    }

    // ---- epilogue
    const int col   = cg * 16 + m;
    const int batch = rb >> 11;
    const int seq0  = rb & (S - 1);
    #pragma unroll
    for (int h = 0; h < 2; ++h) {
        const int orow = rb + mh * 32 + h * 16 + g * 4;
        #pragma unroll
        for (int r = 0; r < 4; ++r) {
            qo[(size_t)(orow + r) * Hd + col] = f2bf(accq[h][r] * 0.125f);
            ko[(size_t)(orow + r) * Hd + col] = f2bf(acck[h][r]);
        }
    }
    #pragma unroll
    for (int ns = 0; ns < 2; ++ns)
        #pragma unroll
        for (int r = 0; r < 4; ++r) {
            const int hc = cg * 16 + g * 4 + r;
            vTo[(size_t)batch * Hd * S + (size_t)hc * S + seq0 + mh * 32 + ns * 16 + m]
                = f2bf(accv[ns][r]);
        }
}

// ---------------------------------------------------------------------------
// Attention v10 (R1-measured version, untouched): LDS-staged K/V with
// coalesced uint4 loads, swapped-operand QK^T, lane-local PV via 16x16x16.
__global__ __launch_bounds__(256)
void attn_part(const ushort_t* __restrict__ q, const ushort_t* __restrict__ k,
               const ushort_t* __restrict__ vT,
               float* __restrict__ lp, ushort_t* __restrict__ op)
{
    const int bi     = blockIdx.x;
    const int parity = bi & 3;
    const int pr     = bi >> 2;
    const int batch  = pr & 7;
    const int tile   = 31 - (pr >> 3);   // longest-first
    const int qs0    = tile * 64;
    const int sidx   = (batch * 32 + tile) * 4 + parity;

    const ushort_t* kb  = k  + (size_t)batch * S * Hd;
    const ushort_t* vTb = vT + (size_t)batch * Hd * S;

    const int t    = threadIdx.x;
    const int w    = t >> 6;
    const int lane = t & 63;
    const int m    = lane & 15;
    const int g    = lane >> 4;

    __shared__ alignas(16) ushort_t KS [64][LSTA];
    __shared__ alignas(16) ushort_t VTS[64][LSTA];

    const ushort_t* qrow = q + (size_t)(batch * S + qs0 + w * 16 + m) * Hd;
    short8 qf0 = *(const short8*)(qrow + g * 8);
    short8 qf1 = *(const short8*)(qrow + 32 + g * 8);

    f32x4 o[4];
    #pragma unroll
    for (int j = 0; j < 4; ++j) o[j] = (f32x4){0.f, 0.f, 0.f, 0.f};
    float lrun = 0.f;
    const int qr = w * 16 + m;   // q row within the 64-row block (mask)

    const int r1 = t >> 3, c16 = (t & 7) * 8;
    uint4 pk0, pk1, pv0, pv1;

    int c = parity;
    if (c <= tile) {
        const int key0 = c * 64;
        const ushort_t* kt_base = kb + (size_t)key0 * Hd;   // 8 KB flat
        pk0 = *(const uint4*)(kt_base + t * 8);
        pk1 = *(const uint4*)(kt_base + (t + 256) * 8);
        pv0 = *(const uint4*)(vTb + (size_t)r1 * S + key0 + c16);
        pv1 = *(const uint4*)(vTb + (size_t)(r1 + 32) * S + key0 + c16);
    }

    for (; c <= tile; c += 4) {
        *(uint4*)&KS [r1][c16]       = pk0;
        *(uint4*)&KS [r1 + 32][c16]  = pk1;
        *(uint4*)&VTS[r1][c16]       = pv0;
        *(uint4*)&VTS[r1 + 32][c16]  = pv1;
        __syncthreads();

        if (c + 4 <= tile) {
            const int key0n = (c + 4) * 64;
            const ushort_t* kt_base = kb + (size_t)key0n * Hd;
            pk0 = *(const uint4*)(kt_base + t * 8);
            pk1 = *(const uint4*)(kt_base + (t + 256) * 8);
            pv0 = *(const uint4*)(vTb + (size_t)r1 * S + key0n + c16);
            pv1 = *(const uint4*)(vTb + (size_t)(r1 + 32) * S + key0n + c16);
        }

        // ---- S^T = K Q^T: sacc[nt][r] = S[q = w*16+m][key = nt*16+g*4+r]
        f32x4 sacc[4];
        #pragma unroll
        for (int j = 0; j < 4; ++j) sacc[j] = (f32x4){0.f, 0.f, 0.f, 0.f};
        #pragma unroll
        for (int nt = 0; nt < 4; ++nt) {
            short8 b0 = *(const short8*)&KS[nt * 16 + m][g * 8];
            short8 b1 = *(const short8*)&KS[nt * 16 + m][32 + g * 8];
            sacc[nt] = __builtin_amdgcn_mfma_f32_16x16x32_bf16(b0, qf0, sacc[nt], 0, 0, 0);
            sacc[nt] = __builtin_amdgcn_mfma_f32_16x16x32_bf16(b1, qf1, sacc[nt], 0, 0, 0);
        }

        // ---- P = exp(S), causal mask on the diagonal tile (no max shift)
        if (c == tile) {
            #pragma unroll
            for (int nt = 0; nt < 4; ++nt)
                #pragma unroll
                for (int r = 0; r < 4; ++r) {
                    const int keyl = nt * 16 + g * 4 + r;
                    sacc[nt][r] = (keyl > qr) ? 0.f : __expf(sacc[nt][r]);
                }
        } else {
            #pragma unroll
            for (int nt = 0; nt < 4; ++nt)
                #pragma unroll
                for (int r = 0; r < 4; ++r)
                    sacc[nt][r] = __expf(sacc[nt][r]);
        }

        // ---- per-lane l accumulation (q fixed = m per lane)
        #pragma unroll
        for (int nt = 0; nt < 4; ++nt)
            lrun += (sacc[nt][0] + sacc[nt][1]) + (sacc[nt][2] + sacc[nt][3]);

        // ---- pack P to bf16 (pairs -> v_cvt_pk_bf16_f32)
        unsigned pw0[4], pw1[4];
        #pragma unroll
        for (int s = 0; s < 4; ++s) {
            pw0[s] = packbf2(sacc[s][0], sacc[s][1]);
            pw1[s] = packbf2(sacc[s][2], sacc[s][3]);
        }

        // ---- O += P V via 16x16x16 (A-frag lane-local: no LDS, no shuffle)
        #pragma unroll
        for (int s = 0; s < 4; ++s) {
            short4v pa;
            { unsigned u2[2] = {pw0[s], pw1[s]}; __builtin_memcpy(&pa, u2, 8); }
            #pragma unroll
            for (int nt = 0; nt < 4; ++nt) {
                short4v vb = *(const short4v*)&VTS[nt * 16 + m][s * 16 + g * 4];
                o[nt] = __builtin_amdgcn_mfma_f32_16x16x16bf16_1k(pa, vb, o[nt], 0, 0, 0);
            }
        }
        __syncthreads();
    }

    // ---- final reduce of l across the 4 g-groups (q = m), write partial
    {
        float ts = lrun;
        ts += __shfl_xor(ts, 16, 64);
        ts += __shfl_xor(ts, 32, 64);
        if (lane < 16) lp[sidx * 64 + w * 16 + m] = ts;
    }
    #pragma unroll
    for (int nt = 0; nt < 4; ++nt)
        #pragma unroll
        for (int r = 0; r < 4; ++r)
            op[(size_t)sidx * 4096 + (w * 16 + g * 4 + r) * 64 + nt * 16 + m]
                = f2bf(o[nt][r]);
}

// ---------------------------------------------------------------------------
// Attention phase 2: plain sum-merge of 4 parity partials. Grid 256.
__global__ __launch_bounds__(256)
void attn_merge(const float* __restrict__ lp, const ushort_t* __restrict__ op,
                float* __restrict__ out)
{
    const int bq    = blockIdx.x;
    const int batch = bq >> 5;
    const int tile  = bq & 31;
    const int s0    = (batch * 32 + tile) * 4;

    const int t   = threadIdx.x;
    const int row = t >> 2;
    const int c16 = (t & 3) * 16;

    float l = 0.f;
    #pragma unroll
    for (int p = 0; p < 4; ++p) l += lp[(s0 + p) * 64 + row];
    const float inv = 1.f / l;

    float acc[16];
    #pragma unroll
    for (int j = 0; j < 16; ++j) acc[j] = 0.f;
    #pragma unroll
    for (int p = 0; p < 4; ++p) {
        short8 a0 = *(const short8*)(op + (size_t)(s0 + p) * 4096 + row * 64 + c16);
        short8 a1 = *(const short8*)(op + (size_t)(s0 + p) * 4096 + row * 64 + c16 + 8);
        #pragma unroll
        for (int j = 0; j < 8; ++j) {
            acc[j]     += bf2f((ushort_t)a0[j]);
            acc[j + 8] += bf2f((ushort_t)a1[j]);
        }
    }
    float* dst = out + (size_t)(batch * S + tile * 64 + row) * Hd + c16;
    #pragma unroll
    for (int j = 0; j < 16; ++j) dst[j] = acc[j] * inv;
}

// ---------------------------------------------------------------------------
extern "C" void kernel_launch(void* const* d_in, const int* in_sizes, int n_in,
                              void* d_out, int out_size, void* d_ws, size_t ws_size,
                              hipStream_t stream) {
    const float* x  = (const float*)d_in[0];
    const float* Wk = (const float*)d_in[1];
    const float* Wq = (const float*)d_in[2];
    const float* Wv = (const float*)d_in[3];
    float* out = (float*)d_out;

    ushort_t* qws  = (ushort_t*)d_ws;                      // 16384*64 bf16
    ushort_t* kws  = qws + (size_t)ROWS * Hd;
    ushort_t* vTws = kws + (size_t)ROWS * Hd;              // [8][64][2048] bf16
    ushort_t* WT   = vTws + (size_t)ROWS * Hd;             // 192*1024 bf16
    float*    lpp  = (float*)(WT + (size_t)NTOT * E);      // 1024*64 f32
    ushort_t* opp  = (ushort_t*)(lpp + 1024 * 64);         // 1024*4096 bf16

    prep_wt<<<(NTOT * E) / 256, 256, 0, stream>>>(Wk, Wq, Wv, WT);
    proj_v12<<<ROWS / BM, 512, 0, stream>>>(x, WT, qws, kws, vTws);
    attn_part<<<1024, 256, 0, stream>>>(qws, kws, vTws, lpp, opp);
    attn_merge<<<256, 256, 0, stream>>>(lpp, opp, out);
}